// Round 1
// baseline (690.140 us; speedup 1.0000x reference)
//
#include <hip/hip_runtime.h>
#include <hip/hip_bf16.h>

typedef unsigned short u16;
typedef __attribute__((ext_vector_type(8))) short bfrag;   // 8 x bf16 (4 VGPRs)
typedef __attribute__((ext_vector_type(4))) float ffrag;   // 4 x f32

// ---- problem constants ----
#define NWIN_TOT 1024      // B_ = 16 * 64 windows
#define NTOK 64            // tokens per window
#define CDIM 512
#define NHEAD 16
#define HDIM 32
#define NW 64              // mask windows

__device__ __forceinline__ u16 f2bf(float f) {
  union { float f; unsigned u; } v; v.f = f;
  unsigned r = v.u + 0x7fffu + ((v.u >> 16) & 1u);
  return (u16)(r >> 16);
}

__device__ __forceinline__ ffrag mfma16(bfrag a, bfrag b, ffrag c) {
  return __builtin_amdgcn_mfma_f32_16x16x32_bf16(a, b, c, 0, 0, 0);
}

// ---------------------------------------------------------------------------
// prep: convert weights to bf16; build transposed bias/mask tables
//   biasT[h][c][r] = rpb[rel_index[r][c]*16 + h]   (16*64*64 f32)
//   maskT[w][c][r] = mask[w][r][c]                 (64*64*64 f32)
// total threads = 786432 + 262144 + 65536 + 262144 = 1376256 = 5376*256
// ---------------------------------------------------------------------------
__global__ __launch_bounds__(256) void k_prep(const float* __restrict__ qkv_w,
                                              const float* __restrict__ proj_w,
                                              const int*   __restrict__ rel_index,
                                              const float* __restrict__ rpb,
                                              const float* __restrict__ mask,
                                              u16* __restrict__ wq, u16* __restrict__ wp,
                                              float* __restrict__ biasT,
                                              float* __restrict__ maskT) {
  int i = blockIdx.x * 256 + threadIdx.x;
  if (i < 786432) { wq[i] = f2bf(qkv_w[i]); return; }
  i -= 786432;
  if (i < 262144) { wp[i] = f2bf(proj_w[i]); return; }
  i -= 262144;
  if (i < 65536) {
    int h = i >> 12, rem = i & 4095, c = rem >> 6, r = rem & 63;
    biasT[i] = rpb[rel_index[r * 64 + c] * 16 + h];
    return;
  }
  i -= 65536;
  if (i < 262144) {
    int w0 = i >> 12, c = (i >> 6) & 63, r = i & 63;
    maskT[i] = mask[(w0 << 12) + r * 64 + c];
  }
}

// ---------------------------------------------------------------------------
// QKV GEMM: per-window block. qkv = x(64x512) @ W^T(1536x512) + b
// q scaled by hd^-0.5, stored [bh][tok][d]; k same; v stored transposed [bh][d][tok]
// ---------------------------------------------------------------------------
__global__ __launch_bounds__(256) void k_qkv(const float* __restrict__ x,
                                             const float* __restrict__ qkv_b,
                                             const u16* __restrict__ wq,
                                             u16* __restrict__ qws, u16* __restrict__ kws,
                                             u16* __restrict__ vws) {
  __shared__ __align__(16) u16 xs[NTOK * CDIM];   // 64 KiB, swizzled
  const int tid = threadIdx.x;
  const int b = blockIdx.x;
  const float* xb = x + (size_t)b * (NTOK * CDIM);

  // stage x -> bf16 LDS with XOR swizzle (elem: col ^ ((row&7)<<3))
#pragma unroll
  for (int it = 0; it < 16; ++it) {
    int e = it * 2048 + tid * 8;
    int row = e >> 9, col = e & 511;
    const float4* xp = reinterpret_cast<const float4*>(xb + e);
    float4 lo = xp[0], hi = xp[1];
    union { u16 u[8]; bfrag v; } pk;
    pk.u[0] = f2bf(lo.x); pk.u[1] = f2bf(lo.y); pk.u[2] = f2bf(lo.z); pk.u[3] = f2bf(lo.w);
    pk.u[4] = f2bf(hi.x); pk.u[5] = f2bf(hi.y); pk.u[6] = f2bf(hi.z); pk.u[7] = f2bf(hi.w);
    int off = row * 512 + (col ^ ((row & 7) << 3));
    *reinterpret_cast<bfrag*>(&xs[off]) = pk.v;
  }
  __syncthreads();

  const int w = tid >> 6, lane = tid & 63, c15 = lane & 15, g = lane >> 4;
  const ffrag zf = {0.f, 0.f, 0.f, 0.f};

  // wave owns 24 col-tiles (cols w*384 .. w*384+383), processed 4 at a time
  for (int cc = 0; cc < 6; ++cc) {
    int ct0 = w * 24 + cc * 4;
    ffrag acc[4][4];
#pragma unroll
    for (int c4 = 0; c4 < 4; ++c4)
#pragma unroll
      for (int i = 0; i < 4; ++i) acc[c4][i] = zf;

    for (int ks = 0; ks < 16; ++ks) {
      int ke = ks * 32 + g * 8;
      bfrag af[4];
#pragma unroll
      for (int i = 0; i < 4; ++i) {
        int row = i * 16 + c15;
        af[i] = *reinterpret_cast<const bfrag*>(&xs[row * 512 + (ke ^ ((row & 7) << 3))]);
      }
#pragma unroll
      for (int c4 = 0; c4 < 4; ++c4) {
        int col = (ct0 + c4) * 16 + c15;
        bfrag bf = *reinterpret_cast<const bfrag*>(wq + (size_t)col * 512 + ke);
#pragma unroll
        for (int i = 0; i < 4; ++i) acc[c4][i] = mfma16(af[i], bf, acc[c4][i]);
      }
    }

#pragma unroll
    for (int c4 = 0; c4 < 4; ++c4) {
      int col0 = (ct0 + c4) * 16;
      int col = col0 + c15;
      float qb = qkv_b[col];
      int which = col0 >> 9;           // 0=q 1=k 2=v
      int hcol = col0 & 511;
      int h = hcol >> 5, dbase = hcol & 31;
      if (which == 2) {
        u16* vp = vws + ((size_t)(b * NHEAD + h) * HDIM + dbase + c15) * NTOK;
#pragma unroll
        for (int i = 0; i < 4; ++i)
#pragma unroll
          for (int r = 0; r < 4; ++r) {
            int tok = i * 16 + g * 4 + r;
            vp[tok] = f2bf(acc[c4][i][r] + qb);
          }
      } else {
        float s = (which == 0) ? 0.17677669529663687f : 1.0f;  // hd^-0.5 for q
        u16* qp = (which == 0 ? qws : kws) + (size_t)(b * NHEAD + h) * (NTOK * HDIM) + dbase + c15;
#pragma unroll
        for (int i = 0; i < 4; ++i)
#pragma unroll
          for (int r = 0; r < 4; ++r) {
            int tok = i * 16 + g * 4 + r;
            qp[(size_t)tok * HDIM] = f2bf((acc[c4][i][r] + qb) * s);
          }
      }
    }
  }
}

// ---------------------------------------------------------------------------
// attention: 1 wave per (window, head). S^T = mfma(K,Q); softmax in-lane+2shfl;
// P -> swizzled LDS -> A-frags; out = P@V via vT; y stored bf16 [b][tok][C]
// ---------------------------------------------------------------------------
__global__ __launch_bounds__(256) void k_attn(const u16* __restrict__ qws,
                                              const u16* __restrict__ kws,
                                              const u16* __restrict__ vws,
                                              const float* __restrict__ biasT,
                                              const float* __restrict__ maskT,
                                              u16* __restrict__ yws) {
  __shared__ __align__(16) u16 plds[4][NTOK * NTOK];  // 8 KiB per wave
  const int tid = threadIdx.x, w = tid >> 6, lane = tid & 63;
  const int c15 = lane & 15, g = lane >> 4, g4 = g * 4;
  const int p = blockIdx.x * 4 + w;
  const int b = p >> 4, h = p & 15;

  const u16* qb_ = qws + (size_t)p * (NTOK * HDIM);
  const u16* kb_ = kws + (size_t)p * (NTOK * HDIM);
  bfrag qa[4], ka[4];
#pragma unroll
  for (int t = 0; t < 4; ++t) {
    qa[t] = *reinterpret_cast<const bfrag*>(qb_ + (t * 16 + c15) * HDIM + g * 8);
    ka[t] = *reinterpret_cast<const bfrag*>(kb_ + (t * 16 + c15) * HDIM + g * 8);
  }

  const float* bT = biasT + h * 4096;
  const float* mT = maskT + (b & (NW - 1)) * 4096;
  u16* pl = plds[w];
  const ffrag zf = {0.f, 0.f, 0.f, 0.f};

#pragma unroll
  for (int it = 0; it < 4; ++it) {
    int row = it * 16 + c15;           // score row
    float l[4][4];
    float mx = -3.0e38f;
#pragma unroll
    for (int jt = 0; jt < 4; ++jt) {
      ffrag s = mfma16(ka[jt], qa[it], zf);   // S^T tile: D[4g+r][c15]
#pragma unroll
      for (int r = 0; r < 4; ++r) {
        int col = jt * 16 + g4 + r;    // score col
        float v = s[r] + bT[col * 64 + row] + mT[col * 64 + row];
        l[jt][r] = v;
        mx = fmaxf(mx, v);
      }
    }
    mx = fmaxf(mx, __shfl_xor(mx, 16));
    mx = fmaxf(mx, __shfl_xor(mx, 32));
    float sum = 0.f;
#pragma unroll
    for (int jt = 0; jt < 4; ++jt)
#pragma unroll
      for (int r = 0; r < 4; ++r) {
        float e = __expf(l[jt][r] - mx);
        l[jt][r] = e;
        sum += e;
      }
    sum += __shfl_xor(sum, 16);
    sum += __shfl_xor(sum, 32);
    float inv = 1.0f / sum;
#pragma unroll
    for (int jt = 0; jt < 4; ++jt) {
      union { u16 u[4]; uint2 v; } pk;
#pragma unroll
      for (int r = 0; r < 4; ++r) pk.u[r] = f2bf(l[jt][r] * inv);
      int off = row * 64 + ((jt * 16 + g4) ^ ((row & 7) << 3));
      *reinterpret_cast<uint2*>(&pl[off]) = pk.v;
    }
  }
  __syncthreads();

  const u16* vb_ = vws + (size_t)p * (HDIM * NTOK);
#pragma unroll
  for (int ct = 0; ct < 2; ++ct) {
    ffrag o[4] = {zf, zf, zf, zf};
#pragma unroll
    for (int ks = 0; ks < 2; ++ks) {
      bfrag vf = *reinterpret_cast<const bfrag*>(vb_ + (ct * 16 + c15) * NTOK + ks * 32 + g * 8);
#pragma unroll
      for (int i = 0; i < 4; ++i) {
        int prow = i * 16 + c15;
        bfrag pa = *reinterpret_cast<const bfrag*>(
            &pl[prow * 64 + ((ks * 32 + g * 8) ^ ((prow & 7) << 3))]);
        o[i] = mfma16(pa, vf, o[i]);
      }
    }
#pragma unroll
    for (int i = 0; i < 4; ++i)
#pragma unroll
      for (int r = 0; r < 4; ++r) {
        int tok = i * 16 + g4 + r;
        yws[((size_t)b * NTOK + tok) * CDIM + h * HDIM + ct * 16 + c15] = f2bf(o[i][r]);
      }
  }
}

// ---------------------------------------------------------------------------
// proj GEMM: per-window block. out = y(64x512) @ proj_w^T(512x512) + proj_b (f32)
// ---------------------------------------------------------------------------
__global__ __launch_bounds__(256) void k_proj(const u16* __restrict__ yws,
                                              const u16* __restrict__ wp,
                                              const float* __restrict__ proj_b,
                                              float* __restrict__ out) {
  __shared__ __align__(16) u16 ys[NTOK * CDIM];
  const int tid = threadIdx.x;
  const int b = blockIdx.x;
  const u16* yb = yws + (size_t)b * (NTOK * CDIM);
#pragma unroll
  for (int it = 0; it < 16; ++it) {
    int e = it * 2048 + tid * 8;
    int row = e >> 9, col = e & 511;
    bfrag v = *reinterpret_cast<const bfrag*>(yb + e);
    *reinterpret_cast<bfrag*>(&ys[row * 512 + (col ^ ((row & 7) << 3))]) = v;
  }
  __syncthreads();

  const int w = tid >> 6, lane = tid & 63, c15 = lane & 15, g = lane >> 4;
  const ffrag zf = {0.f, 0.f, 0.f, 0.f};

  for (int cc = 0; cc < 2; ++cc) {
    int ct0 = w * 8 + cc * 4;
    ffrag acc[4][4];
#pragma unroll
    for (int c4 = 0; c4 < 4; ++c4)
#pragma unroll
      for (int i = 0; i < 4; ++i) acc[c4][i] = zf;

    for (int ks = 0; ks < 16; ++ks) {
      int ke = ks * 32 + g * 8;
      bfrag af[4];
#pragma unroll
      for (int i = 0; i < 4; ++i) {
        int row = i * 16 + c15;
        af[i] = *reinterpret_cast<const bfrag*>(&ys[row * 512 + (ke ^ ((row & 7) << 3))]);
      }
#pragma unroll
      for (int c4 = 0; c4 < 4; ++c4) {
        int col = (ct0 + c4) * 16 + c15;
        bfrag bf = *reinterpret_cast<const bfrag*>(wp + (size_t)col * 512 + ke);
#pragma unroll
        for (int i = 0; i < 4; ++i) acc[c4][i] = mfma16(af[i], bf, acc[c4][i]);
      }
    }

#pragma unroll
    for (int c4 = 0; c4 < 4; ++c4) {
      int col = (ct0 + c4) * 16 + c15;
      float pb = proj_b[col];
#pragma unroll
      for (int i = 0; i < 4; ++i)
#pragma unroll
        for (int r = 0; r < 4; ++r) {
          int row = i * 16 + g * 4 + r;
          out[((size_t)b * NTOK + row) * CDIM + col] = acc[c4][i][r] + pb;
        }
    }
  }
}

// ---------------------------------------------------------------------------
extern "C" void kernel_launch(void* const* d_in, const int* in_sizes, int n_in,
                              void* d_out, int out_size, void* d_ws, size_t ws_size,
                              hipStream_t stream) {
  const float* x      = (const float*)d_in[0];
  const float* mask   = (const float*)d_in[1];
  const float* qkv_w  = (const float*)d_in[2];
  const float* qkv_b  = (const float*)d_in[3];
  const float* proj_w = (const float*)d_in[4];
  const float* proj_b = (const float*)d_in[5];
  const float* rpb    = (const float*)d_in[6];
  const int*   rel    = (const int*)d_in[7];
  float* out = (float*)d_out;

  char* ws = (char*)d_ws;
  constexpr size_t SZ_QKV = (size_t)NWIN_TOT * NHEAD * NTOK * HDIM * 2;  // 64 MiB each
  u16* qws = (u16*)(ws);
  u16* kws = (u16*)(ws + SZ_QKV);
  u16* vws = (u16*)(ws + 2 * SZ_QKV);
  u16* yws = (u16*)(ws + 3 * SZ_QKV);
  u16* wq  = (u16*)(ws + 4 * SZ_QKV);
  u16* wp  = (u16*)(ws + 4 * SZ_QKV + 1572864);
  float* biasT = (float*)(ws + 4 * SZ_QKV + 1572864 + 524288);
  float* maskT = (float*)(ws + 4 * SZ_QKV + 1572864 + 524288 + 262144);

  k_prep<<<dim3(5376), dim3(256), 0, stream>>>(qkv_w, proj_w, rel, rpb, mask, wq, wp, biasT, maskT);
  k_qkv<<<dim3(NWIN_TOT), dim3(256), 0, stream>>>(x, qkv_b, wq, qws, kws, vws);
  k_attn<<<dim3(NWIN_TOT * NHEAD / 4), dim3(256), 0, stream>>>(qws, kws, vws, biasT, maskT, yws);
  k_proj<<<dim3(NWIN_TOT), dim3(256), 0, stream>>>(yws, wp, proj_b, out);
}

// Round 2
// 441.829 us; speedup vs baseline: 1.5620x; 1.5620x over previous
//
#include <hip/hip_runtime.h>
#include <hip/hip_bf16.h>

typedef unsigned short u16;
typedef __attribute__((ext_vector_type(8))) short bfrag;   // 8 x bf16 (4 VGPRs)
typedef __attribute__((ext_vector_type(4))) float ffrag;   // 4 x f32

// ---- problem constants ----
#define NWIN_TOT 1024      // B_ = 16 * 64 windows
#define NTOK 64            // tokens per window
#define CDIM 512
#define NHEAD 16
#define HDIM 32
#define NW 64              // mask windows
#define MROWS (NWIN_TOT * NTOK)   // 65536 GEMM rows

__device__ __forceinline__ u16 f2bf(float f) {
  union { float f; unsigned u; } v; v.f = f;
  unsigned r = v.u + 0x7fffu + ((v.u >> 16) & 1u);
  return (u16)(r >> 16);
}

__device__ __forceinline__ ffrag mfma16(bfrag a, bfrag b, ffrag c) {
  return __builtin_amdgcn_mfma_f32_16x16x32_bf16(a, b, c, 0, 0, 0);
}

// async global->LDS, 16B per lane, linear LDS dest (wave base + lane*16)
__device__ __forceinline__ void gload16(const u16* src, u16* lds) {
#if __has_builtin(__builtin_amdgcn_global_load_lds)
  __builtin_amdgcn_global_load_lds(
      (const __attribute__((address_space(1))) unsigned int*)src,
      (__attribute__((address_space(3))) unsigned int*)lds, 16, 0, 0);
#else
  *reinterpret_cast<bfrag*>(lds) = *reinterpret_cast<const bfrag*>(src);
#endif
}

// ---------------------------------------------------------------------------
// prep: x -> bf16; weights -> bf16; transposed bias/mask tables
// threads: 4194304 (xb) + 786432 (wq) + 262144 (wp) + 65536 (biasT) + 262144 (maskT)
//        = 5570560 = 21760 * 256
// ---------------------------------------------------------------------------
__global__ __launch_bounds__(256) void k_prep(const float* __restrict__ x,
                                              const float* __restrict__ qkv_w,
                                              const float* __restrict__ proj_w,
                                              const int*   __restrict__ rel_index,
                                              const float* __restrict__ rpb,
                                              const float* __restrict__ mask,
                                              u16* __restrict__ xb,
                                              u16* __restrict__ wq, u16* __restrict__ wp,
                                              float* __restrict__ biasT,
                                              float* __restrict__ maskT) {
  int i = blockIdx.x * 256 + threadIdx.x;
  if (i < 4194304) {            // x -> bf16, 8 elems/thread
    int e = i * 8;
    const float4* xp = reinterpret_cast<const float4*>(x + e);
    float4 lo = xp[0], hi = xp[1];
    union { u16 u[8]; bfrag v; } pk;
    pk.u[0] = f2bf(lo.x); pk.u[1] = f2bf(lo.y); pk.u[2] = f2bf(lo.z); pk.u[3] = f2bf(lo.w);
    pk.u[4] = f2bf(hi.x); pk.u[5] = f2bf(hi.y); pk.u[6] = f2bf(hi.z); pk.u[7] = f2bf(hi.w);
    *reinterpret_cast<bfrag*>(xb + e) = pk.v;
    return;
  }
  i -= 4194304;
  if (i < 786432) { wq[i] = f2bf(qkv_w[i]); return; }
  i -= 786432;
  if (i < 262144) { wp[i] = f2bf(proj_w[i]); return; }
  i -= 262144;
  if (i < 65536) {
    int h = i >> 12, rem = i & 4095, c = rem >> 6, r = rem & 63;
    biasT[i] = rpb[rel_index[r * 64 + c] * 16 + h];
    return;
  }
  i -= 65536;
  if (i < 262144) {
    int w0 = i >> 12, c = (i >> 6) & 63, r = i & 63;
    maskT[i] = mask[(w0 << 12) + r * 64 + c];
  }
}

// ---------------------------------------------------------------------------
// Tiled GEMM, m97 structure: 128x128 tile, BK=64, 4 waves (each 64x64 out),
// global_load_lds w16 with pre-swizzled source, XOR-swizzled ds_read_b128.
// C[m][n] = sum_k A[m][k] * W[n][k]   (B^T layout)
// EPI 0: qkv epilogue (bias, q-scale, split q/k/vT, bf16)
// EPI 1: proj epilogue (bias, f32 out)
// ---------------------------------------------------------------------------
template<int EPI>
__global__ __launch_bounds__(256) void k_gemm(const u16* __restrict__ A,
                                              const u16* __restrict__ W,
                                              const float* __restrict__ bias,
                                              u16* __restrict__ qws, u16* __restrict__ kws,
                                              u16* __restrict__ vws,
                                              float* __restrict__ out) {
  constexpr int NT = (EPI == 0) ? 12 : 4;          // N / 128
  __shared__ __align__(16) u16 As[128 * 64];       // 16 KiB, swizzled layout
  __shared__ __align__(16) u16 Bs[128 * 64];       // 16 KiB

  // XCD-bijective swizzle; N-inner so blocks sharing an A-panel are adjacent
  const int cpx = (512 * NT) >> 3;
  const int bid = blockIdx.x;
  const int tile = (bid & 7) * cpx + (bid >> 3);
  const int bn = tile % NT, bm = tile / NT;
  const int brow = bm << 7, bcol = bn << 7;

  const int tid = threadIdx.x;
  const int wv = tid >> 6, lane = tid & 63, c15 = lane & 15, g = lane >> 4;
  const int wr = wv >> 1, wc = wv & 1;
  const ffrag zf = {0.f, 0.f, 0.f, 0.f};

  ffrag acc[4][4];
#pragma unroll
  for (int i = 0; i < 4; ++i)
#pragma unroll
    for (int n = 0; n < 4; ++n) acc[i][n] = zf;

  const char* Asb = reinterpret_cast<const char*>(As);
  const char* Bsb = reinterpret_cast<const char*>(Bs);

  for (int kt = 0; kt < 8; ++kt) {
    const int k0 = kt << 6;
    // stage: linear LDS dest, inverse-swizzled global source (G21)
#pragma unroll
    for (int it = 0; it < 4; ++it) {
      int e = it * 2048 + tid * 8;                 // element index in tile
      int row = e >> 6;
      int cb = (e & 63) << 1;                      // byte col, 16-aligned
      int scol = (cb ^ ((row & 7) << 4)) >> 1;     // source element col
      gload16(A + (size_t)(brow + row) * 512 + k0 + scol, As + e);
      gload16(W + (size_t)(bcol + row) * 512 + k0 + scol, Bs + e);
    }
    __syncthreads();
#pragma unroll
    for (int ks = 0; ks < 2; ++ks) {
      const int kb = ks * 64 + g * 16;             // byte col within row
      bfrag af[4], bf[4];
#pragma unroll
      for (int i = 0; i < 4; ++i) {
        int ra = wr * 64 + i * 16 + c15;
        af[i] = *reinterpret_cast<const bfrag*>(Asb + ra * 128 + (kb ^ ((ra & 7) << 4)));
        int rb = wc * 64 + i * 16 + c15;
        bf[i] = *reinterpret_cast<const bfrag*>(Bsb + rb * 128 + (kb ^ ((rb & 7) << 4)));
      }
#pragma unroll
      for (int i = 0; i < 4; ++i)
#pragma unroll
        for (int n = 0; n < 4; ++n)
          acc[i][n] = mfma16(af[i], bf[n], acc[i][n]);
    }
    if (kt < 7) __syncthreads();
  }

  // epilogue: D frag mapping col = c15, row = g*4 + r
  if (EPI == 0) {
    const float SCALE = 0.17677669529663687f;      // 32^-0.5
#pragma unroll
    for (int n = 0; n < 4; ++n) {
      int c = bcol + wc * 64 + n * 16 + c15;       // 0..1535
      float bz = bias[c];
      int which = c >> 9;                          // block-uniform: 0=q 1=k 2=v
      int cq = c & 511, h = cq >> 5, d = cq & 31;
#pragma unroll
      for (int i = 0; i < 4; ++i) {
        int m0 = brow + wr * 64 + i * 16 + g * 4;
#pragma unroll
        for (int r = 0; r < 4; ++r) {
          int m = m0 + r, b = m >> 6, tok = m & 63;
          float val = acc[i][n][r] + bz;
          if (which == 0)
            qws[((size_t)(b * NHEAD + h) * NTOK + tok) * HDIM + d] = f2bf(val * SCALE);
          else if (which == 1)
            kws[((size_t)(b * NHEAD + h) * NTOK + tok) * HDIM + d] = f2bf(val);
          else
            vws[((size_t)(b * NHEAD + h) * HDIM + d) * NTOK + tok] = f2bf(val);
        }
      }
    }
  } else {
#pragma unroll
    for (int n = 0; n < 4; ++n) {
      int c = bcol + wc * 64 + n * 16 + c15;
      float bz = bias[c];
#pragma unroll
      for (int i = 0; i < 4; ++i) {
        int m0 = brow + wr * 64 + i * 16 + g * 4;
#pragma unroll
        for (int r = 0; r < 4; ++r) {
          int m = m0 + r;
          out[(size_t)m * CDIM + c] = acc[i][n][r] + bz;
        }
      }
    }
  }
}

// ---------------------------------------------------------------------------
// attention: 1 wave per (window, head). S^T = mfma(K,Q); softmax in-lane+2shfl;
// P -> swizzled LDS -> A-frags; out = P@V via vT; y stored bf16 [b][tok][C]
// ---------------------------------------------------------------------------
__global__ __launch_bounds__(256) void k_attn(const u16* __restrict__ qws,
                                              const u16* __restrict__ kws,
                                              const u16* __restrict__ vws,
                                              const float* __restrict__ biasT,
                                              const float* __restrict__ maskT,
                                              u16* __restrict__ yws) {
  __shared__ __align__(16) u16 plds[4][NTOK * NTOK];  // 8 KiB per wave
  const int tid = threadIdx.x, w = tid >> 6, lane = tid & 63;
  const int c15 = lane & 15, g = lane >> 4, g4 = g * 4;
  const int p = blockIdx.x * 4 + w;
  const int b = p >> 4, h = p & 15;

  const u16* qb_ = qws + (size_t)p * (NTOK * HDIM);
  const u16* kb_ = kws + (size_t)p * (NTOK * HDIM);
  bfrag qa[4], ka[4];
#pragma unroll
  for (int t = 0; t < 4; ++t) {
    qa[t] = *reinterpret_cast<const bfrag*>(qb_ + (t * 16 + c15) * HDIM + g * 8);
    ka[t] = *reinterpret_cast<const bfrag*>(kb_ + (t * 16 + c15) * HDIM + g * 8);
  }

  const float* bT = biasT + h * 4096;
  const float* mT = maskT + (b & (NW - 1)) * 4096;
  u16* pl = plds[w];
  const ffrag zf = {0.f, 0.f, 0.f, 0.f};

#pragma unroll
  for (int it = 0; it < 4; ++it) {
    int row = it * 16 + c15;           // score row
    float l[4][4];
    float mx = -3.0e38f;
#pragma unroll
    for (int jt = 0; jt < 4; ++jt) {
      ffrag s = mfma16(ka[jt], qa[it], zf);   // S^T tile: D[4g+r][c15]
#pragma unroll
      for (int r = 0; r < 4; ++r) {
        int col = jt * 16 + g4 + r;    // score col
        float v = s[r] + bT[col * 64 + row] + mT[col * 64 + row];
        l[jt][r] = v;
        mx = fmaxf(mx, v);
      }
    }
    mx = fmaxf(mx, __shfl_xor(mx, 16));
    mx = fmaxf(mx, __shfl_xor(mx, 32));
    float sum = 0.f;
#pragma unroll
    for (int jt = 0; jt < 4; ++jt)
#pragma unroll
      for (int r = 0; r < 4; ++r) {
        float e = __expf(l[jt][r] - mx);
        l[jt][r] = e;
        sum += e;
      }
    sum += __shfl_xor(sum, 16);
    sum += __shfl_xor(sum, 32);
    float inv = 1.0f / sum;
#pragma unroll
    for (int jt = 0; jt < 4; ++jt) {
      union { u16 u[4]; uint2 v; } pk;
#pragma unroll
      for (int r = 0; r < 4; ++r) pk.u[r] = f2bf(l[jt][r] * inv);
      int off = row * 64 + ((jt * 16 + g4) ^ ((row & 7) << 3));
      *reinterpret_cast<uint2*>(&pl[off]) = pk.v;
    }
  }
  __syncthreads();

  const u16* vb_ = vws + (size_t)p * (HDIM * NTOK);
#pragma unroll
  for (int ct = 0; ct < 2; ++ct) {
    ffrag o[4] = {zf, zf, zf, zf};
#pragma unroll
    for (int ks = 0; ks < 2; ++ks) {
      bfrag vf = *reinterpret_cast<const bfrag*>(vb_ + (ct * 16 + c15) * NTOK + ks * 32 + g * 8);
#pragma unroll
      for (int i = 0; i < 4; ++i) {
        int prow = i * 16 + c15;
        bfrag pa = *reinterpret_cast<const bfrag*>(
            &pl[prow * 64 + ((ks * 32 + g * 8) ^ ((prow & 7) << 3))]);
        o[i] = mfma16(pa, vf, o[i]);
      }
    }
#pragma unroll
    for (int i = 0; i < 4; ++i)
#pragma unroll
      for (int r = 0; r < 4; ++r) {
        int tok = i * 16 + g4 + r;
        yws[((size_t)b * NTOK + tok) * CDIM + h * HDIM + ct * 16 + c15] = f2bf(o[i][r]);
      }
  }
}

// ---------------------------------------------------------------------------
extern "C" void kernel_launch(void* const* d_in, const int* in_sizes, int n_in,
                              void* d_out, int out_size, void* d_ws, size_t ws_size,
                              hipStream_t stream) {
  const float* x      = (const float*)d_in[0];
  const float* mask   = (const float*)d_in[1];
  const float* qkv_w  = (const float*)d_in[2];
  const float* qkv_b  = (const float*)d_in[3];
  const float* proj_w = (const float*)d_in[4];
  const float* proj_b = (const float*)d_in[5];
  const float* rpb    = (const float*)d_in[6];
  const int*   rel    = (const int*)d_in[7];
  float* out = (float*)d_out;

  char* ws = (char*)d_ws;
  constexpr size_t SZ_QKV = (size_t)NWIN_TOT * NHEAD * NTOK * HDIM * 2;  // 64 MiB each
  u16* qws = (u16*)(ws);
  u16* kws = (u16*)(ws + SZ_QKV);
  u16* vws = (u16*)(ws + 2 * SZ_QKV);
  u16* xb  = (u16*)(ws + 3 * SZ_QKV);   // x as bf16; dead after k_gemm<0> ...
  u16* yws = xb;                        // ... so yws aliases it (written in k_attn)
  u16* wq  = (u16*)(ws + 4 * SZ_QKV);
  u16* wp  = (u16*)(ws + 4 * SZ_QKV + 1572864);
  float* biasT = (float*)(ws + 4 * SZ_QKV + 1572864 + 524288);
  float* maskT = (float*)(ws + 4 * SZ_QKV + 1572864 + 524288 + 262144);

  k_prep<<<dim3(21760), dim3(256), 0, stream>>>(x, qkv_w, proj_w, rel, rpb, mask,
                                                xb, wq, wp, biasT, maskT);
  k_gemm<0><<<dim3(512 * 12), dim3(256), 0, stream>>>(xb, wq, qkv_b, qws, kws, vws, nullptr);
  k_attn<<<dim3(NWIN_TOT * NHEAD / 4), dim3(256), 0, stream>>>(qws, kws, vws, biasT, maskT, yws);
  k_gemm<1><<<dim3(512 * 4), dim3(256), 0, stream>>>(yws, wp, proj_b, nullptr, nullptr, nullptr, out);
}

// Round 4
// 402.552 us; speedup vs baseline: 1.7144x; 1.0976x over previous
//
#include <hip/hip_runtime.h>
#include <hip/hip_bf16.h>

typedef unsigned short u16;
typedef __attribute__((ext_vector_type(8))) short bfrag;   // 8 x bf16 (4 VGPRs)
typedef __attribute__((ext_vector_type(4))) float ffrag;   // 4 x f32

// ---- problem constants ----
#define NWIN_TOT 1024      // B_ = 16 * 64 windows
#define NTOK 64            // tokens per window
#define CDIM 512
#define NHEAD 16
#define HDIM 32
#define NW 64              // mask windows

__device__ __forceinline__ u16 f2bf(float f) {
  union { float f; unsigned u; } v; v.f = f;
  unsigned r = v.u + 0x7fffu + ((v.u >> 16) & 1u);
  return (u16)(r >> 16);
}

__device__ __forceinline__ ffrag mfma16(bfrag a, bfrag b, ffrag c) {
  return __builtin_amdgcn_mfma_f32_16x16x32_bf16(a, b, c, 0, 0, 0);
}

// async global->LDS, 16B per lane, linear LDS dest (wave base + lane*16)
__device__ __forceinline__ void gload16(const u16* src, u16* lds) {
  __builtin_amdgcn_global_load_lds(
      (const __attribute__((address_space(1))) unsigned int*)src,
      (__attribute__((address_space(3))) unsigned int*)lds, 16, 0, 0);
}

#define BAR() __builtin_amdgcn_s_barrier()
#define LGKM0() do { asm volatile("s_waitcnt lgkmcnt(0)" ::: "memory"); \
                     __builtin_amdgcn_sched_barrier(0); } while (0)
#define VMW(n) do { asm volatile("s_waitcnt vmcnt(" #n ")" ::: "memory"); \
                    __builtin_amdgcn_sched_barrier(0); } while (0)

// ---------------------------------------------------------------------------
// prep: x -> bf16; weights -> bf16; transposed bias/mask tables
// ---------------------------------------------------------------------------
__global__ __launch_bounds__(256) void k_prep(const float* __restrict__ x,
                                              const float* __restrict__ qkv_w,
                                              const float* __restrict__ proj_w,
                                              const int*   __restrict__ rel_index,
                                              const float* __restrict__ rpb,
                                              const float* __restrict__ mask,
                                              u16* __restrict__ xb,
                                              u16* __restrict__ wq, u16* __restrict__ wp,
                                              float* __restrict__ biasT,
                                              float* __restrict__ maskT) {
  int i = blockIdx.x * 256 + threadIdx.x;
  if (i < 4194304) {            // x -> bf16, 8 elems/thread
    int e = i * 8;
    const float4* xp = reinterpret_cast<const float4*>(x + e);
    float4 lo = xp[0], hi = xp[1];
    union { u16 u[8]; bfrag v; } pk;
    pk.u[0] = f2bf(lo.x); pk.u[1] = f2bf(lo.y); pk.u[2] = f2bf(lo.z); pk.u[3] = f2bf(lo.w);
    pk.u[4] = f2bf(hi.x); pk.u[5] = f2bf(hi.y); pk.u[6] = f2bf(hi.z); pk.u[7] = f2bf(hi.w);
    *reinterpret_cast<bfrag*>(xb + e) = pk.v;
    return;
  }
  i -= 4194304;
  if (i < 786432) { wq[i] = f2bf(qkv_w[i]); return; }
  i -= 786432;
  if (i < 262144) { wp[i] = f2bf(proj_w[i]); return; }
  i -= 262144;
  if (i < 65536) {
    int h = i >> 12, rem = i & 4095, c = rem >> 6, r = rem & 63;
    biasT[i] = rpb[rel_index[r * 64 + c] * 16 + h];
    return;
  }
  i -= 65536;
  if (i < 262144) {
    int w0 = i >> 12, c = (i >> 6) & 63, r = i & 63;
    maskT[i] = mask[(w0 << 12) + r * 64 + c];
  }
}

// ---------------------------------------------------------------------------
// 8-phase 256x256 GEMM, BK=64, 8 waves (2M x 4N), K=512 (8 K-tiles).
// LDS 128 KiB dynamic: [buf][A,B][256][64] bf16; buf = t&1.
//
// Region-lifetime ledger (buf cur):
//   B half0/half1: last ds_read at P2 (wc 0/1 rows 32-63,96-127; wc 2/3 mirror)
//                  -> overwrite legal from P3 (after P2 trailing barrier)
//   A half0/half1: last ds_read at P3 (wr0 rows 64-127; wr1 rows 192-255)
//                  -> overwrite legal from P4 (after P3 trailing barrier)
// Stage placement: P3 stages (t+2, B, 0/1); P4 stages (t+2, A, 0/1).
// vmcnt(8) at P4 drains everything older than this iter's 4 stages
// => tile t+1 fully resident before t+1 begins. Tail: t==6 -> vmcnt(0).
// ---------------------------------------------------------------------------
#define MFMAQ(mh, nh, BARR) \
  _Pragma("unroll") for (int i_ = 0; i_ < 4; ++i_) \
  _Pragma("unroll") for (int n_ = 0; n_ < 2; ++n_) \
  _Pragma("unroll") for (int ks_ = 0; ks_ < 2; ++ks_) \
    acc[(mh)*4+i_][(nh)*2+n_] = mfma16(a_[i_*2+ks_], BARR[n_*2+ks_], acc[(mh)*4+i_][(nh)*2+n_]);

template<int EPI>
__global__ __launch_bounds__(512, 2) void k_gemm8(const u16* __restrict__ A,
                                                  const u16* __restrict__ W,
                                                  const float* __restrict__ bias,
                                                  u16* __restrict__ qws, u16* __restrict__ kws,
                                                  u16* __restrict__ vws,
                                                  float* __restrict__ out) {
  constexpr int NT = (EPI == 0) ? 6 : 2;           // N / 256
  constexpr int NWG = 256 * NT;                    // grid size (M/256 * NT)
  extern __shared__ __align__(16) u16 smem[];      // [2][2][256][64] = 128 KiB

  // XCD-bijective swizzle (NWG % 8 == 0), N-inner tile order
  const int bid = blockIdx.x;
  const int tile = (bid & 7) * (NWG >> 3) + (bid >> 3);
  const int bn = tile % NT, bm = tile / NT;
  const int brow = bm << 8, bcol = bn << 8;

  const int tid = threadIdx.x;
  const int wv = tid >> 6, lane = tid & 63, c15 = lane & 15, g = lane >> 4;
  const int wr = wv >> 2, wc = wv & 3;             // 2 x 4 wave grid
  const int rowA0 = wr * 128 + c15;                // + mh*64 + i*16
  const int rowB0 = wc * 64 + c15;                 // + nh*32 + n*16
  const ffrag zf = {0.f, 0.f, 0.f, 0.f};

  ffrag acc[8][4];
#pragma unroll
  for (int i = 0; i < 8; ++i)
#pragma unroll
    for (int n = 0; n < 4; ++n) acc[i][n] = zf;

  // stage one half-tile (128 rows x 64 cols) of matrix mat for K-tile t
  auto stage = [&](int t, int mat, int half) {
    u16* db = smem + ((t & 1) * 2 + mat) * 16384 + half * 8192;
    const u16* gsrc = mat ? W : A;
    const int gr0 = (mat ? bcol : brow) + half * 128;
#pragma unroll
    for (int l = 0; l < 2; ++l) {
      int e = l * 4096 + tid * 8;                  // elem in half-tile
      int r = e >> 6, cb = (e & 63) << 1;          // row, byte-col (16-aligned)
      int scol = (cb ^ ((r & 7) << 4)) >> 1;       // inverse-swizzled source col
      gload16(gsrc + (size_t)(gr0 + r) * 512 + t * 64 + scol, db + e);
    }
  };

  // prologue: tiles 0 and 1 (16 loads); vmcnt(8) => tile0 fully resident
  stage(0, 0, 0); stage(0, 0, 1); stage(0, 1, 0); stage(0, 1, 1);
  stage(1, 0, 0); stage(1, 0, 1); stage(1, 1, 0); stage(1, 1, 1);
  VMW(8);
  BAR();

  for (int t = 0; t < 8; ++t) {
    const char* As_ = (const char*)(smem + ((t & 1) * 2 + 0) * 16384);
    const char* Bs_ = (const char*)(smem + ((t & 1) * 2 + 1) * 16384);
    bfrag a_[8], b0_[4], b1_[4];

    // ---- P1: ds A(mh0) + B(nh0); no stages ----
#pragma unroll
    for (int i = 0; i < 4; ++i) {
      int ra = rowA0 + i * 16;
#pragma unroll
      for (int ks = 0; ks < 2; ++ks)
        a_[i * 2 + ks] = *(const bfrag*)(As_ + ra * 128 + ((ks * 64 + g * 16) ^ ((ra & 7) << 4)));
    }
#pragma unroll
    for (int n = 0; n < 2; ++n) {
      int rb = rowB0 + n * 16;
#pragma unroll
      for (int ks = 0; ks < 2; ++ks)
        b0_[n * 2 + ks] = *(const bfrag*)(Bs_ + rb * 128 + ((ks * 64 + g * 16) ^ ((rb & 7) << 4)));
    }
    BAR(); LGKM0();
    __builtin_amdgcn_s_setprio(1);
    MFMAQ(0, 0, b0_);
    __builtin_amdgcn_s_setprio(0);
    BAR();

    // ---- P2: ds B(nh1); no stages ----
#pragma unroll
    for (int n = 0; n < 2; ++n) {
      int rb = rowB0 + 32 + n * 16;
#pragma unroll
      for (int ks = 0; ks < 2; ++ks)
        b1_[n * 2 + ks] = *(const bfrag*)(Bs_ + rb * 128 + ((ks * 64 + g * 16) ^ ((rb & 7) << 4)));
    }
    BAR(); LGKM0();
    __builtin_amdgcn_s_setprio(1);
    MFMAQ(0, 1, b1_);
    __builtin_amdgcn_s_setprio(0);
    BAR();

    // ---- P3: ds A(mh1); stage t+2 B halves (B regions free after P2 bar) ----
#pragma unroll
    for (int i = 0; i < 4; ++i) {
      int ra = rowA0 + 64 + i * 16;
#pragma unroll
      for (int ks = 0; ks < 2; ++ks)
        a_[i * 2 + ks] = *(const bfrag*)(As_ + ra * 128 + ((ks * 64 + g * 16) ^ ((ra & 7) << 4)));
    }
    if (t + 2 < 8) { stage(t + 2, 1, 0); stage(t + 2, 1, 1); }
    BAR(); LGKM0();
    __builtin_amdgcn_s_setprio(1);
    MFMAQ(1, 1, b1_);
    __builtin_amdgcn_s_setprio(0);
    BAR();

    // ---- P4: stage t+2 A halves (A regions free after P3 bar); reuse a_/b0_ ----
    if (t + 2 < 8) { stage(t + 2, 0, 0); stage(t + 2, 0, 1); }
    BAR();
    __builtin_amdgcn_s_setprio(1);
    MFMAQ(1, 0, b0_);
    __builtin_amdgcn_s_setprio(0);
    if (t < 6) { VMW(8); } else if (t == 6) { VMW(0); }
    BAR();
  }

  // epilogue: D frag mapping col = c15, row = g*4 + r
  if (EPI == 0) {
    const float SCALE = 0.17677669529663687f;      // 32^-0.5
#pragma unroll
    for (int n = 0; n < 4; ++n) {
      int c = bcol + wc * 64 + n * 16 + c15;       // 0..1535
      float bz = bias[c];
      int which = c >> 9;                          // block-uniform: 0=q 1=k 2=v
      int cq = c & 511, h = cq >> 5, d = cq & 31;
#pragma unroll
      for (int i = 0; i < 8; ++i) {
        int m0 = brow + wr * 128 + i * 16 + g * 4;
#pragma unroll
        for (int r = 0; r < 4; ++r) {
          int m = m0 + r, b = m >> 6, tok = m & 63;
          float val = acc[i][n][r] + bz;
          if (which == 0)
            qws[((size_t)(b * NHEAD + h) * NTOK + tok) * HDIM + d] = f2bf(val * SCALE);
          else if (which == 1)
            kws[((size_t)(b * NHEAD + h) * NTOK + tok) * HDIM + d] = f2bf(val);
          else
            vws[((size_t)(b * NHEAD + h) * HDIM + d) * NTOK + tok] = f2bf(val);
        }
      }
    }
  } else {
#pragma unroll
    for (int n = 0; n < 4; ++n) {
      int c = bcol + wc * 64 + n * 16 + c15;
      float bz = bias[c];
#pragma unroll
      for (int i = 0; i < 8; ++i) {
        int m0 = brow + wr * 128 + i * 16 + g * 4;
#pragma unroll
        for (int r = 0; r < 4; ++r) {
          int m = m0 + r;
          out[(size_t)m * CDIM + c] = acc[i][n][r] + bz;
        }
      }
    }
  }
}

// ---------------------------------------------------------------------------
// attention: 1 wave per (window, head). S^T = mfma(K,Q); softmax in-lane+2shfl;
// P -> swizzled LDS -> A-frags; out = P@V via vT; y stored bf16 [b][tok][C]
// ---------------------------------------------------------------------------
__global__ __launch_bounds__(256) void k_attn(const u16* __restrict__ qws,
                                              const u16* __restrict__ kws,
                                              const u16* __restrict__ vws,
                                              const float* __restrict__ biasT,
                                              const float* __restrict__ maskT,
                                              u16* __restrict__ yws) {
  __shared__ __align__(16) u16 plds[4][NTOK * NTOK];  // 8 KiB per wave
  const int tid = threadIdx.x, w = tid >> 6, lane = tid & 63;
  const int c15 = lane & 15, g = lane >> 4, g4 = g * 4;
  const int p = blockIdx.x * 4 + w;
  const int b = p >> 4, h = p & 15;

  const u16* qb_ = qws + (size_t)p * (NTOK * HDIM);
  const u16* kb_ = kws + (size_t)p * (NTOK * HDIM);
  bfrag qa[4], ka[4];
#pragma unroll
  for (int t = 0; t < 4; ++t) {
    qa[t] = *reinterpret_cast<const bfrag*>(qb_ + (t * 16 + c15) * HDIM + g * 8);
    ka[t] = *reinterpret_cast<const bfrag*>(kb_ + (t * 16 + c15) * HDIM + g * 8);
  }

  const float* bT = biasT + h * 4096;
  const float* mT = maskT + (b & (NW - 1)) * 4096;
  u16* pl = plds[w];
  const ffrag zf = {0.f, 0.f, 0.f, 0.f};

#pragma unroll
  for (int it = 0; it < 4; ++it) {
    int row = it * 16 + c15;           // score row
    float l[4][4];
    float mx = -3.0e38f;
#pragma unroll
    for (int jt = 0; jt < 4; ++jt) {
      ffrag s = mfma16(ka[jt], qa[it], zf);   // S^T tile: D[4g+r][c15]
#pragma unroll
      for (int r = 0; r < 4; ++r) {
        int col = jt * 16 + g4 + r;    // score col
        float v = s[r] + bT[col * 64 + row] + mT[col * 64 + row];
        l[jt][r] = v;
        mx = fmaxf(mx, v);
      }
    }
    mx = fmaxf(mx, __shfl_xor(mx, 16));
    mx = fmaxf(mx, __shfl_xor(mx, 32));
    float sum = 0.f;
#pragma unroll
    for (int jt = 0; jt < 4; ++jt)
#pragma unroll
      for (int r = 0; r < 4; ++r) {
        float e = __expf(l[jt][r] - mx);
        l[jt][r] = e;
        sum += e;
      }
    sum += __shfl_xor(sum, 16);
    sum += __shfl_xor(sum, 32);
    float inv = 1.0f / sum;
#pragma unroll
    for (int jt = 0; jt < 4; ++jt) {
      union { u16 u[4]; uint2 v; } pk;
#pragma unroll
      for (int r = 0; r < 4; ++r) pk.u[r] = f2bf(l[jt][r] * inv);
      int off = row * 64 + ((jt * 16 + g4) ^ ((row & 7) << 3));
      *reinterpret_cast<uint2*>(&pl[off]) = pk.v;
    }
  }
  __syncthreads();

  const u16* vb_ = vws + (size_t)p * (HDIM * NTOK);
#pragma unroll
  for (int ct = 0; ct < 2; ++ct) {
    ffrag o[4] = {zf, zf, zf, zf};
#pragma unroll
    for (int ks = 0; ks < 2; ++ks) {
      bfrag vf = *reinterpret_cast<const bfrag*>(vb_ + (ct * 16 + c15) * NTOK + ks * 32 + g * 8);
#pragma unroll
      for (int i = 0; i < 4; ++i) {
        int prow = i * 16 + c15;
        bfrag pa = *reinterpret_cast<const bfrag*>(
            &pl[prow * 64 + ((ks * 32 + g * 8) ^ ((prow & 7) << 3))]);
        o[i] = mfma16(pa, vf, o[i]);
      }
    }
#pragma unroll
    for (int i = 0; i < 4; ++i)
#pragma unroll
      for (int r = 0; r < 4; ++r) {
        int tok = i * 16 + g4 + r;
        yws[((size_t)b * NTOK + tok) * CDIM + h * HDIM + ct * 16 + c15] = f2bf(o[i][r]);
      }
  }
}

// ---------------------------------------------------------------------------
extern "C" void kernel_launch(void* const* d_in, const int* in_sizes, int n_in,
                              void* d_out, int out_size, void* d_ws, size_t ws_size,
                              hipStream_t stream) {
  const float* x      = (const float*)d_in[0];
  const float* mask   = (const float*)d_in[1];
  const float* qkv_w  = (const float*)d_in[2];
  const float* qkv_b  = (const float*)d_in[3];
  const float* proj_w = (const float*)d_in[4];
  const float* proj_b = (const float*)d_in[5];
  const float* rpb    = (const float*)d_in[6];
  const int*   rel    = (const int*)d_in[7];
  float* out = (float*)d_out;

  char* ws = (char*)d_ws;
  constexpr size_t SZ_QKV = (size_t)NWIN_TOT * NHEAD * NTOK * HDIM * 2;  // 64 MiB each
  u16* qws = (u16*)(ws);
  u16* kws = (u16*)(ws + SZ_QKV);
  u16* vws = (u16*)(ws + 2 * SZ_QKV);
  u16* xb  = (u16*)(ws + 3 * SZ_QKV);   // x as bf16; dead after k_gemm8<0> ...
  u16* yws = xb;                        // ... so yws aliases it (written in k_attn)
  u16* wq  = (u16*)(ws + 4 * SZ_QKV);
  u16* wp  = (u16*)(ws + 4 * SZ_QKV + 1572864);
  float* biasT = (float*)(ws + 4 * SZ_QKV + 1572864 + 524288);
  float* maskT = (float*)(ws + 4 * SZ_QKV + 1572864 + 524288 + 262144);

  hipFuncSetAttribute((const void*)k_gemm8<0>,
                      hipFuncAttributeMaxDynamicSharedMemorySize, 131072);
  hipFuncSetAttribute((const void*)k_gemm8<1>,
                      hipFuncAttributeMaxDynamicSharedMemorySize, 131072);

  k_prep<<<dim3(21760), dim3(256), 0, stream>>>(x, qkv_w, proj_w, rel, rpb, mask,
                                                xb, wq, wp, biasT, maskT);
  k_gemm8<0><<<dim3(256 * 6), dim3(512), 131072, stream>>>(xb, wq, qkv_b, qws, kws, vws, nullptr);
  k_attn<<<dim3(NWIN_TOT * NHEAD / 4), dim3(256), 0, stream>>>(qws, kws, vws, biasT, maskT, yws);
  k_gemm8<1><<<dim3(256 * 2), dim3(512), 131072, stream>>>(yws, wp, proj_b, nullptr, nullptr, nullptr, out);
}

// Round 5
// 351.453 us; speedup vs baseline: 1.9637x; 1.1454x over previous
//
#include <hip/hip_runtime.h>
#include <hip/hip_bf16.h>

typedef unsigned short u16;
typedef __attribute__((ext_vector_type(8))) short bfrag;   // 8 x bf16 (4 VGPRs)
typedef __attribute__((ext_vector_type(4))) float ffrag;   // 4 x f32

// ---- problem constants ----
#define NWIN_TOT 1024      // B_ = 16 * 64 windows
#define NTOK 64            // tokens per window
#define CDIM 512
#define NHEAD 16
#define HDIM 32
#define NW 64              // mask windows

__device__ __forceinline__ u16 f2bf(float f) {
  union { float f; unsigned u; } v; v.f = f;
  unsigned r = v.u + 0x7fffu + ((v.u >> 16) & 1u);
  return (u16)(r >> 16);
}

__device__ __forceinline__ ffrag mfma16(bfrag a, bfrag b, ffrag c) {
  return __builtin_amdgcn_mfma_f32_16x16x32_bf16(a, b, c, 0, 0, 0);
}

// async global->LDS, 16B per lane, linear LDS dest (wave base + lane*16)
__device__ __forceinline__ void gload16(const u16* src, u16* lds) {
  __builtin_amdgcn_global_load_lds(
      (const __attribute__((address_space(1))) unsigned int*)src,
      (__attribute__((address_space(3))) unsigned int*)lds, 16, 0, 0);
}

#define BAR() __builtin_amdgcn_s_barrier()
#define SCHED0() __builtin_amdgcn_sched_barrier(0)
#define VMW(n) do { asm volatile("s_waitcnt vmcnt(" #n ")" ::: "memory"); \
                    __builtin_amdgcn_sched_barrier(0); } while (0)

// ---------------------------------------------------------------------------
// prep: x -> bf16; weights -> bf16; transposed bias/mask tables
// ---------------------------------------------------------------------------
__global__ __launch_bounds__(256) void k_prep(const float* __restrict__ x,
                                              const float* __restrict__ qkv_w,
                                              const float* __restrict__ proj_w,
                                              const int*   __restrict__ rel_index,
                                              const float* __restrict__ rpb,
                                              const float* __restrict__ mask,
                                              u16* __restrict__ xb,
                                              u16* __restrict__ wq, u16* __restrict__ wp,
                                              float* __restrict__ biasT,
                                              float* __restrict__ maskT) {
  int i = blockIdx.x * 256 + threadIdx.x;
  if (i < 4194304) {            // x -> bf16, 8 elems/thread
    int e = i * 8;
    const float4* xp = reinterpret_cast<const float4*>(x + e);
    float4 lo = xp[0], hi = xp[1];
    union { u16 u[8]; bfrag v; } pk;
    pk.u[0] = f2bf(lo.x); pk.u[1] = f2bf(lo.y); pk.u[2] = f2bf(lo.z); pk.u[3] = f2bf(lo.w);
    pk.u[4] = f2bf(hi.x); pk.u[5] = f2bf(hi.y); pk.u[6] = f2bf(hi.z); pk.u[7] = f2bf(hi.w);
    *reinterpret_cast<bfrag*>(xb + e) = pk.v;
    return;
  }
  i -= 4194304;
  if (i < 786432) { wq[i] = f2bf(qkv_w[i]); return; }
  i -= 786432;
  if (i < 262144) { wp[i] = f2bf(proj_w[i]); return; }
  i -= 262144;
  if (i < 65536) {
    int h = i >> 12, rem = i & 4095, c = rem >> 6, r = rem & 63;
    biasT[i] = rpb[rel_index[r * 64 + c] * 16 + h];
    return;
  }
  i -= 65536;
  if (i < 262144) {
    int w0 = i >> 12, c = (i >> 6) & 63, r = i & 63;
    maskT[i] = mask[(w0 << 12) + r * 64 + c];
  }
}

// ---------------------------------------------------------------------------
// 8-phase 256x256 GEMM, BK=64, 8 waves (2M x 4N), K=512 (8 K-tiles).
// LDS 128 KiB dynamic: [buf][A,B][256][64] bf16; buf = t&1.
//
// Region-lifetime ledger (buf cur) — unchanged from R4 (verified):
//   B halves: last ds_read issued at P2, consumed (lgkm-awaited by compiler)
//             before P2's MFMAs -> complete before P2 trailing barrier
//             -> overwrite legal from P3.
//   A halves: last ds_read at P3, complete before P3 trailing barrier
//             -> overwrite legal from P4.
// Stage placement: P3 stages (t+2, B, 0/1); P4 stages (t+2, A, 0/1).
// vmcnt(8) at P4 drains everything older than this iter's 4 stages
// => tile t+1 fully resident before t+1 begins. Tail: t==6 -> vmcnt(0).
// NOTE: no explicit lgkmcnt(0) — ds_reads are compiler-visible, so hipcc
// emits fine-grained per-consumer lgkmcnt, overlapping LDS service with MFMA.
// ---------------------------------------------------------------------------
#define MFMAQ(mh, nh, BARR) \
  _Pragma("unroll") for (int i_ = 0; i_ < 4; ++i_) \
  _Pragma("unroll") for (int n_ = 0; n_ < 2; ++n_) \
  _Pragma("unroll") for (int ks_ = 0; ks_ < 2; ++ks_) \
    acc[(mh)*4+i_][(nh)*2+n_] = mfma16(a_[i_*2+ks_], BARR[n_*2+ks_], acc[(mh)*4+i_][(nh)*2+n_]);

template<int EPI>
__global__ __launch_bounds__(512, 2) void k_gemm8(const u16* __restrict__ A,
                                                  const u16* __restrict__ W,
                                                  const float* __restrict__ bias,
                                                  u16* __restrict__ qws, u16* __restrict__ kws,
                                                  u16* __restrict__ vws,
                                                  float* __restrict__ out) {
  constexpr int NT = (EPI == 0) ? 6 : 2;           // N / 256
  constexpr int NWG = 256 * NT;                    // grid size (M/256 * NT)
  extern __shared__ __align__(16) u16 smem[];      // [2][2][256][64] = 128 KiB

  // XCD-bijective swizzle (NWG % 8 == 0), N-inner tile order
  const int bid = blockIdx.x;
  const int tile = (bid & 7) * (NWG >> 3) + (bid >> 3);
  const int bn = tile % NT, bm = tile / NT;
  const int brow = bm << 8, bcol = bn << 8;

  const int tid = threadIdx.x;
  const int wv = tid >> 6, lane = tid & 63, c15 = lane & 15, g = lane >> 4;
  const int wr = wv >> 2, wc = wv & 3;             // 2 x 4 wave grid
  const int rowA0 = wr * 128 + c15;                // + mh*64 + i*16
  const int rowB0 = wc * 64 + c15;                 // + nh*32 + n*16
  const ffrag zf = {0.f, 0.f, 0.f, 0.f};

  ffrag acc[8][4];
#pragma unroll
  for (int i = 0; i < 8; ++i)
#pragma unroll
    for (int n = 0; n < 4; ++n) acc[i][n] = zf;

  // stage one half-tile (128 rows x 64 cols) of matrix mat for K-tile t
  auto stage = [&](int t, int mat, int half) {
    u16* db = smem + ((t & 1) * 2 + mat) * 16384 + half * 8192;
    const u16* gsrc = mat ? W : A;
    const int gr0 = (mat ? bcol : brow) + half * 128;
#pragma unroll
    for (int l = 0; l < 2; ++l) {
      int e = l * 4096 + tid * 8;                  // elem in half-tile
      int r = e >> 6, cb = (e & 63) << 1;          // row, byte-col (16-aligned)
      int scol = (cb ^ ((r & 7) << 4)) >> 1;       // inverse-swizzled source col
      gload16(gsrc + (size_t)(gr0 + r) * 512 + t * 64 + scol, db + e);
    }
  };

  // prologue: tiles 0 and 1 (16 loads); vmcnt(8) => tile0 fully resident
  stage(0, 0, 0); stage(0, 0, 1); stage(0, 1, 0); stage(0, 1, 1);
  stage(1, 0, 0); stage(1, 0, 1); stage(1, 1, 0); stage(1, 1, 1);
  VMW(8);
  BAR();

  for (int t = 0; t < 8; ++t) {
    const char* As_ = (const char*)(smem + ((t & 1) * 2 + 0) * 16384);
    const char* Bs_ = (const char*)(smem + ((t & 1) * 2 + 1) * 16384);
    bfrag a_[8], b0_[4], b1_[4];

    // ---- P1: ds A(mh0) + B(nh0); no stages ----
#pragma unroll
    for (int i = 0; i < 4; ++i) {
      int ra = rowA0 + i * 16;
#pragma unroll
      for (int ks = 0; ks < 2; ++ks)
        a_[i * 2 + ks] = *(const bfrag*)(As_ + ra * 128 + ((ks * 64 + g * 16) ^ ((ra & 7) << 4)));
    }
#pragma unroll
    for (int n = 0; n < 2; ++n) {
      int rb = rowB0 + n * 16;
#pragma unroll
      for (int ks = 0; ks < 2; ++ks)
        b0_[n * 2 + ks] = *(const bfrag*)(Bs_ + rb * 128 + ((ks * 64 + g * 16) ^ ((rb & 7) << 4)));
    }
    BAR();
    __builtin_amdgcn_s_setprio(1);
    MFMAQ(0, 0, b0_);
    __builtin_amdgcn_s_setprio(0);
    BAR();

    // ---- P2: ds B(nh1); no stages ----
#pragma unroll
    for (int n = 0; n < 2; ++n) {
      int rb = rowB0 + 32 + n * 16;
#pragma unroll
      for (int ks = 0; ks < 2; ++ks)
        b1_[n * 2 + ks] = *(const bfrag*)(Bs_ + rb * 128 + ((ks * 64 + g * 16) ^ ((rb & 7) << 4)));
    }
    BAR();
    __builtin_amdgcn_s_setprio(1);
    MFMAQ(0, 1, b1_);
    __builtin_amdgcn_s_setprio(0);
    BAR();

    // ---- P3: ds A(mh1); stage t+2 B halves (B regions free after P2 bar) ----
#pragma unroll
    for (int i = 0; i < 4; ++i) {
      int ra = rowA0 + 64 + i * 16;
#pragma unroll
      for (int ks = 0; ks < 2; ++ks)
        a_[i * 2 + ks] = *(const bfrag*)(As_ + ra * 128 + ((ks * 64 + g * 16) ^ ((ra & 7) << 4)));
    }
    SCHED0();                                      // pin: reads issue before stages
    if (t + 2 < 8) { stage(t + 2, 1, 0); stage(t + 2, 1, 1); }
    BAR();
    __builtin_amdgcn_s_setprio(1);
    MFMAQ(1, 1, b1_);
    __builtin_amdgcn_s_setprio(0);
    BAR();

    // ---- P4: stage t+2 A halves (A regions free after P3 bar); reuse a_/b0_ ----
    if (t + 2 < 8) { stage(t + 2, 0, 0); stage(t + 2, 0, 1); }
    BAR();
    __builtin_amdgcn_s_setprio(1);
    MFMAQ(1, 0, b0_);
    __builtin_amdgcn_s_setprio(0);
    if (t < 6) { VMW(8); } else if (t == 6) { VMW(0); }
    BAR();
  }

  // epilogue: D frag mapping col = c15, row = g*4 + r
  if (EPI == 0) {
    const float SCALE = 0.17677669529663687f;      // 32^-0.5
    const int win0 = (brow + wr * 128) >> 6;       // first window of this wave
#pragma unroll
    for (int n = 0; n < 4; ++n) {
      int c = bcol + wc * 64 + n * 16 + c15;       // 0..1535
      float bz = bias[c];
      int which = c >> 9;                          // block-uniform: 0=q 1=k 2=v
      int cq = c & 511, h = cq >> 5, d = cq & 31;
      size_t pb0 = ((size_t)(win0 * NHEAD + h)) << 11;   // (win,head) slab, 2048 elems
      size_t pb1 = pb0 + ((size_t)NHEAD << 11);          // win0+1
      if (which == 2) {
        u16* v0 = vws + pb0 + (d << 6);
        u16* v1 = vws + pb1 + (d << 6);
#pragma unroll
        for (int i = 0; i < 8; ++i) {
          u16* vp = (i < 4) ? v0 : v1;
#pragma unroll
          for (int r = 0; r < 4; ++r) {
            int tok = (i & 3) * 16 + g * 4 + r;
            vp[tok] = f2bf(acc[i][n][r] + bz);
          }
        }
      } else {
        const float s = (which == 0) ? SCALE : 1.0f;
        u16* base = (which == 0) ? qws : kws;
        u16* q0 = base + pb0 + d;
        u16* q1 = base + pb1 + d;
#pragma unroll
        for (int i = 0; i < 8; ++i) {
          u16* qp = (i < 4) ? q0 : q1;
#pragma unroll
          for (int r = 0; r < 4; ++r) {
            int tok = (i & 3) * 16 + g * 4 + r;
            qp[tok << 5] = f2bf((acc[i][n][r] + bz) * s);
          }
        }
      }
    }
  } else {
#pragma unroll
    for (int n = 0; n < 4; ++n) {
      int c = bcol + wc * 64 + n * 16 + c15;
      float bz = bias[c];
      float* po = out + (size_t)(brow + wr * 128) * CDIM + c;
#pragma unroll
      for (int i = 0; i < 8; ++i)
#pragma unroll
        for (int r = 0; r < 4; ++r)
          po[(size_t)(i * 16 + g * 4 + r) * CDIM] = acc[i][n][r] + bz;
    }
  }
}

// ---------------------------------------------------------------------------
// attention: 1 wave per (window, head). S^T = mfma(K,Q); softmax in-lane+2shfl;
// P -> swizzled LDS -> A-frags; out = P@V via vT; y stored bf16 [b][tok][C]
// ---------------------------------------------------------------------------
__global__ __launch_bounds__(256) void k_attn(const u16* __restrict__ qws,
                                              const u16* __restrict__ kws,
                                              const u16* __restrict__ vws,
                                              const float* __restrict__ biasT,
                                              const float* __restrict__ maskT,
                                              u16* __restrict__ yws) {
  __shared__ __align__(16) u16 plds[4][NTOK * NTOK];  // 8 KiB per wave
  const int tid = threadIdx.x, w = tid >> 6, lane = tid & 63;
  const int c15 = lane & 15, g = lane >> 4, g4 = g * 4;
  const int p = blockIdx.x * 4 + w;
  const int b = p >> 4, h = p & 15;

  const u16* qb_ = qws + (size_t)p * (NTOK * HDIM);
  const u16* kb_ = kws + (size_t)p * (NTOK * HDIM);
  bfrag qa[4], ka[4];
#pragma unroll
  for (int t = 0; t < 4; ++t) {
    qa[t] = *reinterpret_cast<const bfrag*>(qb_ + (t * 16 + c15) * HDIM + g * 8);
    ka[t] = *reinterpret_cast<const bfrag*>(kb_ + (t * 16 + c15) * HDIM + g * 8);
  }

  const float* bT = biasT + h * 4096;
  const float* mT = maskT + (b & (NW - 1)) * 4096;
  u16* pl = plds[w];
  const ffrag zf = {0.f, 0.f, 0.f, 0.f};

#pragma unroll
  for (int it = 0; it < 4; ++it) {
    int row = it * 16 + c15;           // score row
    float l[4][4];
    float mx = -3.0e38f;
#pragma unroll
    for (int jt = 0; jt < 4; ++jt) {
      ffrag s = mfma16(ka[jt], qa[it], zf);   // S^T tile: D[4g+r][c15]
#pragma unroll
      for (int r = 0; r < 4; ++r) {
        int col = jt * 16 + g4 + r;    // score col
        float v = s[r] + bT[col * 64 + row] + mT[col * 64 + row];
        l[jt][r] = v;
        mx = fmaxf(mx, v);
      }
    }
    mx = fmaxf(mx, __shfl_xor(mx, 16));
    mx = fmaxf(mx, __shfl_xor(mx, 32));
    float sum = 0.f;
#pragma unroll
    for (int jt = 0; jt < 4; ++jt)
#pragma unroll
      for (int r = 0; r < 4; ++r) {
        float e = __expf(l[jt][r] - mx);
        l[jt][r] = e;
        sum += e;
      }
    sum += __shfl_xor(sum, 16);
    sum += __shfl_xor(sum, 32);
    float inv = 1.0f / sum;
#pragma unroll
    for (int jt = 0; jt < 4; ++jt) {
      union { u16 u[4]; uint2 v; } pk;
#pragma unroll
      for (int r = 0; r < 4; ++r) pk.u[r] = f2bf(l[jt][r] * inv);
      int off = row * 64 + ((jt * 16 + g4) ^ ((row & 7) << 3));
      *reinterpret_cast<uint2*>(&pl[off]) = pk.v;
    }
  }
  __syncthreads();

  const u16* vb_ = vws + (size_t)p * (HDIM * NTOK);
#pragma unroll
  for (int ct = 0; ct < 2; ++ct) {
    ffrag o[4] = {zf, zf, zf, zf};
#pragma unroll
    for (int ks = 0; ks < 2; ++ks) {
      bfrag vf = *reinterpret_cast<const bfrag*>(vb_ + (ct * 16 + c15) * NTOK + ks * 32 + g * 8);
#pragma unroll
      for (int i = 0; i < 4; ++i) {
        int prow = i * 16 + c15;
        bfrag pa = *reinterpret_cast<const bfrag*>(
            &pl[prow * 64 + ((ks * 32 + g * 8) ^ ((prow & 7) << 3))]);
        o[i] = mfma16(pa, vf, o[i]);
      }
    }
#pragma unroll
    for (int i = 0; i < 4; ++i)
#pragma unroll
      for (int r = 0; r < 4; ++r) {
        int tok = i * 16 + g4 + r;
        yws[((size_t)b * NTOK + tok) * CDIM + h * HDIM + ct * 16 + c15] = f2bf(o[i][r]);
      }
  }
}

// ---------------------------------------------------------------------------
extern "C" void kernel_launch(void* const* d_in, const int* in_sizes, int n_in,
                              void* d_out, int out_size, void* d_ws, size_t ws_size,
                              hipStream_t stream) {
  const float* x      = (const float*)d_in[0];
  const float* mask   = (const float*)d_in[1];
  const float* qkv_w  = (const float*)d_in[2];
  const float* qkv_b  = (const float*)d_in[3];
  const float* proj_w = (const float*)d_in[4];
  const float* proj_b = (const float*)d_in[5];
  const float* rpb    = (const float*)d_in[6];
  const int*   rel    = (const int*)d_in[7];
  float* out = (float*)d_out;

  char* ws = (char*)d_ws;
  constexpr size_t SZ_QKV = (size_t)NWIN_TOT * NHEAD * NTOK * HDIM * 2;  // 64 MiB each
  u16* qws = (u16*)(ws);
  u16* kws = (u16*)(ws + SZ_QKV);
  u16* vws = (u16*)(ws + 2 * SZ_QKV);
  u16* xb  = (u16*)(ws + 3 * SZ_QKV);   // x as bf16; dead after k_gemm8<0> ...
  u16* yws = xb;                        // ... so yws aliases it (written in k_attn)
  u16* wq  = (u16*)(ws + 4 * SZ_QKV);
  u16* wp  = (u16*)(ws + 4 * SZ_QKV + 1572864);
  float* biasT = (float*)(ws + 4 * SZ_QKV + 1572864 + 524288);
  float* maskT = (float*)(ws + 4 * SZ_QKV + 1572864 + 524288 + 262144);

  hipFuncSetAttribute((const void*)k_gemm8<0>,
                      hipFuncAttributeMaxDynamicSharedMemorySize, 131072);
  hipFuncSetAttribute((const void*)k_gemm8<1>,
                      hipFuncAttributeMaxDynamicSharedMemorySize, 131072);

  k_prep<<<dim3(21760), dim3(256), 0, stream>>>(x, qkv_w, proj_w, rel, rpb, mask,
                                                xb, wq, wp, biasT, maskT);
  k_gemm8<0><<<dim3(256 * 6), dim3(512), 131072, stream>>>(xb, wq, qkv_b, qws, kws, vws, nullptr);
  k_attn<<<dim3(NWIN_TOT * NHEAD / 4), dim3(256), 0, stream>>>(qws, kws, vws, biasT, maskT, yws);
  k_gemm8<1><<<dim3(256 * 2), dim3(512), 131072, stream>>>(yws, wp, proj_b, nullptr, nullptr, nullptr, out);
}

// Round 6
// 310.318 us; speedup vs baseline: 2.2240x; 1.1326x over previous
//
#include <hip/hip_runtime.h>
#include <hip/hip_bf16.h>

typedef unsigned short u16;
typedef __attribute__((ext_vector_type(8))) short bfrag;   // 8 x bf16 (4 VGPRs)
typedef __attribute__((ext_vector_type(4))) float ffrag;   // 4 x f32

// ---- problem constants ----
#define NWIN_TOT 1024      // B_ = 16 * 64 windows
#define NTOK 64            // tokens per window
#define CDIM 512
#define NHEAD 16
#define HDIM 32
#define NW 64              // mask windows

__device__ __forceinline__ u16 f2bf(float f) {
  union { float f; unsigned u; } v; v.f = f;
  unsigned r = v.u + 0x7fffu + ((v.u >> 16) & 1u);
  return (u16)(r >> 16);
}

__device__ __forceinline__ float bfhi2f(unsigned hi_bits) {  // bf16 in high 16 bits
  union { unsigned u; float f; } v; v.u = hi_bits; return v.f;
}

__device__ __forceinline__ ffrag mfma16(bfrag a, bfrag b, ffrag c) {
  return __builtin_amdgcn_mfma_f32_16x16x32_bf16(a, b, c, 0, 0, 0);
}

// async global->LDS, 16B per lane, linear LDS dest (wave base + lane*16)
__device__ __forceinline__ void gload16(const u16* src, u16* lds) {
  __builtin_amdgcn_global_load_lds(
      (const __attribute__((address_space(1))) unsigned int*)src,
      (__attribute__((address_space(3))) unsigned int*)lds, 16, 0, 0);
}

#define BAR() __builtin_amdgcn_s_barrier()
#define SCHED0() __builtin_amdgcn_sched_barrier(0)
#define VMW(n) do { asm volatile("s_waitcnt vmcnt(" #n ")" ::: "memory"); \
                    __builtin_amdgcn_sched_barrier(0); } while (0)

// ---------------------------------------------------------------------------
// prep: x -> bf16; weights -> bf16; combined bias+mask table (bf16, row-major)
//   combB[w][h][row][col] = rpb[rel_index[row][col]*16+h] + mask[w][row][col]
// threads: 4194304 (xb) + 786432 (wq) + 262144 (wp) + 4194304 (combB)
//        = 9437184 = 36864 * 256
// ---------------------------------------------------------------------------
__global__ __launch_bounds__(256) void k_prep(const float* __restrict__ x,
                                              const float* __restrict__ qkv_w,
                                              const float* __restrict__ proj_w,
                                              const int*   __restrict__ rel_index,
                                              const float* __restrict__ rpb,
                                              const float* __restrict__ mask,
                                              u16* __restrict__ xb,
                                              u16* __restrict__ wq, u16* __restrict__ wp,
                                              u16* __restrict__ combB) {
  int i = blockIdx.x * 256 + threadIdx.x;
  if (i < 4194304) {            // x -> bf16, 8 elems/thread
    int e = i * 8;
    const float4* xp = reinterpret_cast<const float4*>(x + e);
    float4 lo = xp[0], hi = xp[1];
    union { u16 u[8]; bfrag v; } pk;
    pk.u[0] = f2bf(lo.x); pk.u[1] = f2bf(lo.y); pk.u[2] = f2bf(lo.z); pk.u[3] = f2bf(lo.w);
    pk.u[4] = f2bf(hi.x); pk.u[5] = f2bf(hi.y); pk.u[6] = f2bf(hi.z); pk.u[7] = f2bf(hi.w);
    *reinterpret_cast<bfrag*>(xb + e) = pk.v;
    return;
  }
  i -= 4194304;
  if (i < 786432) { wq[i] = f2bf(qkv_w[i]); return; }
  i -= 786432;
  if (i < 262144) { wp[i] = f2bf(proj_w[i]); return; }
  i -= 262144;
  {                              // combB: i in [0, 4194304)
    int wh = i >> 12, rc = i & 4095;
    int w0 = wh >> 4, h = wh & 15;
    combB[i] = f2bf(rpb[rel_index[rc] * 16 + h] + mask[(w0 << 12) + rc]);
  }
}

// ---------------------------------------------------------------------------
// 8-phase 256x256 GEMM, BK=64, 8 waves (2M x 4N), K=512 (8 K-tiles).
// LDS 128 KiB dynamic: [buf][A,B][256][64] bf16; buf = t&1.
//
// ds_read balance per phase per wave: P1=8(A-lo) P2=4(B-hi) P3=8(A-hi) P4=4(b0 of t+1).
// Region-lifetime ledger (buf cur):
//   B halves: last ds_read at P2 -> overwrite legal from P3 (stage t+2 B).
//   A halves: last ds_read at P3 -> overwrite legal from P4 (stage t+2 A).
// vmcnt ledger: at P4 after its stages, the 8 newest outstanding = tile t+2's;
//   VMW(8) drains tile t+1; the following BARRIER makes that drain cross-wave
//   (each wave's vmcnt covers only its own queue) -> P4's b0_ prefetch of buf
//   nxt is safe AFTER that barrier, never before. t==6: VMW(0) drains tile 7.
// b0_ is loop-carried: read in t's P4 (+ prologue for t=0), used in t+1's P1.
// No explicit lgkmcnt(0): ds_reads are compiler-visible (fine-grained lgkmcnt).
// ---------------------------------------------------------------------------
#define MFMAQ(mh, nh, BARR) \
  _Pragma("unroll") for (int i_ = 0; i_ < 4; ++i_) \
  _Pragma("unroll") for (int n_ = 0; n_ < 2; ++n_) \
  _Pragma("unroll") for (int ks_ = 0; ks_ < 2; ++ks_) \
    acc[(mh)*4+i_][(nh)*2+n_] = mfma16(a_[i_*2+ks_], BARR[n_*2+ks_], acc[(mh)*4+i_][(nh)*2+n_]);

template<int EPI>
__global__ __launch_bounds__(512, 2) void k_gemm8(const u16* __restrict__ A,
                                                  const u16* __restrict__ W,
                                                  const float* __restrict__ bias,
                                                  u16* __restrict__ qws, u16* __restrict__ kws,
                                                  u16* __restrict__ vws,
                                                  float* __restrict__ out) {
  constexpr int NT = (EPI == 0) ? 6 : 2;           // N / 256
  constexpr int NWG = 256 * NT;                    // grid size (M/256 * NT)
  extern __shared__ __align__(16) u16 smem[];      // [2][2][256][64] = 128 KiB

  // XCD-bijective swizzle (NWG % 8 == 0), N-inner tile order
  const int bid = blockIdx.x;
  const int tile = (bid & 7) * (NWG >> 3) + (bid >> 3);
  const int bn = tile % NT, bm = tile / NT;
  const int brow = bm << 8, bcol = bn << 8;

  const int tid = threadIdx.x;
  const int wv = tid >> 6, lane = tid & 63, c15 = lane & 15, g = lane >> 4;
  const int wr = wv >> 2, wc = wv & 3;             // 2 x 4 wave grid
  const int rowA0 = wr * 128 + c15;                // + mh*64 + i*16
  const int rowB0 = wc * 64 + c15;                 // + nh*32 + n*16
  const ffrag zf = {0.f, 0.f, 0.f, 0.f};

  ffrag acc[8][4];
#pragma unroll
  for (int i = 0; i < 8; ++i)
#pragma unroll
    for (int n = 0; n < 4; ++n) acc[i][n] = zf;

  // stage one half-tile (128 rows x 64 cols) of matrix mat for K-tile t
  auto stage = [&](int t, int mat, int half) {
    u16* db = smem + ((t & 1) * 2 + mat) * 16384 + half * 8192;
    const u16* gsrc = mat ? W : A;
    const int gr0 = (mat ? bcol : brow) + half * 128;
#pragma unroll
    for (int l = 0; l < 2; ++l) {
      int e = l * 4096 + tid * 8;                  // elem in half-tile
      int r = e >> 6, cb = (e & 63) << 1;          // row, byte-col (16-aligned)
      int scol = (cb ^ ((r & 7) << 4)) >> 1;       // inverse-swizzled source col
      gload16(gsrc + (size_t)(gr0 + r) * 512 + t * 64 + scol, db + e);
    }
  };

  // prologue: tiles 0 and 1 (16 loads); vmcnt(8)+BAR => tile0 resident chip-wide
  stage(0, 0, 0); stage(0, 0, 1); stage(0, 1, 0); stage(0, 1, 1);
  stage(1, 0, 0); stage(1, 0, 1); stage(1, 1, 0); stage(1, 1, 1);
  VMW(8);
  BAR();

  bfrag b0_[4];                                    // loop-carried (B nh0 of tile t)
  {
    const char* B0_ = (const char*)(smem + 1 * 16384);
#pragma unroll
    for (int n = 0; n < 2; ++n) {
      int rb = rowB0 + n * 16;
#pragma unroll
      for (int ks = 0; ks < 2; ++ks)
        b0_[n * 2 + ks] = *(const bfrag*)(B0_ + rb * 128 + ((ks * 64 + g * 16) ^ ((rb & 7) << 4)));
    }
  }

  for (int t = 0; t < 8; ++t) {
    const char* As_ = (const char*)(smem + ((t & 1) * 2 + 0) * 16384);
    const char* Bs_ = (const char*)(smem + ((t & 1) * 2 + 1) * 16384);
    bfrag a_[8], b1_[4];

    // ---- P1: ds A(mh0) [8]; MFMA Q(0,0) uses b0_ carried from prev P4 ----
#pragma unroll
    for (int i = 0; i < 4; ++i) {
      int ra = rowA0 + i * 16;
#pragma unroll
      for (int ks = 0; ks < 2; ++ks)
        a_[i * 2 + ks] = *(const bfrag*)(As_ + ra * 128 + ((ks * 64 + g * 16) ^ ((ra & 7) << 4)));
    }
    BAR();
    __builtin_amdgcn_s_setprio(1);
    MFMAQ(0, 0, b0_);
    __builtin_amdgcn_s_setprio(0);
    BAR();

    // ---- P2: ds B(nh1) [4] ----
#pragma unroll
    for (int n = 0; n < 2; ++n) {
      int rb = rowB0 + 32 + n * 16;
#pragma unroll
      for (int ks = 0; ks < 2; ++ks)
        b1_[n * 2 + ks] = *(const bfrag*)(Bs_ + rb * 128 + ((ks * 64 + g * 16) ^ ((rb & 7) << 4)));
    }
    BAR();
    __builtin_amdgcn_s_setprio(1);
    MFMAQ(0, 1, b1_);
    __builtin_amdgcn_s_setprio(0);
    BAR();

    // ---- P3: ds A(mh1) [8]; stage t+2 B halves (B regions free after P2 bar) ----
#pragma unroll
    for (int i = 0; i < 4; ++i) {
      int ra = rowA0 + 64 + i * 16;
#pragma unroll
      for (int ks = 0; ks < 2; ++ks)
        a_[i * 2 + ks] = *(const bfrag*)(As_ + ra * 128 + ((ks * 64 + g * 16) ^ ((ra & 7) << 4)));
    }
    SCHED0();                                      // pin: reads issue before stages
    if (t + 2 < 8) { stage(t + 2, 1, 0); stage(t + 2, 1, 1); }
    BAR();
    __builtin_amdgcn_s_setprio(1);
    MFMAQ(1, 1, b1_);
    __builtin_amdgcn_s_setprio(0);
    BAR();

    // ---- P4: stage t+2 A halves (A free after P3 bar); VMW then BAR makes the
    //          t+1 drain cross-wave; prefetch b0_ of t+1 from buf nxt [4] ----
    if (t + 2 < 8) { stage(t + 2, 0, 0); stage(t + 2, 0, 1); }
    if (t < 6) { VMW(8); } else if (t == 6) { VMW(0); }
    BAR();
    __builtin_amdgcn_s_setprio(1);
    MFMAQ(1, 0, b0_);
    __builtin_amdgcn_s_setprio(0);
    if (t < 7) {
      const char* Bn_ = (const char*)(smem + (((t + 1) & 1) * 2 + 1) * 16384);
#pragma unroll
      for (int n = 0; n < 2; ++n) {
        int rb = rowB0 + n * 16;
#pragma unroll
        for (int ks = 0; ks < 2; ++ks)
          b0_[n * 2 + ks] = *(const bfrag*)(Bn_ + rb * 128 + ((ks * 64 + g * 16) ^ ((rb & 7) << 4)));
      }
    }
    BAR();
  }

  // epilogue: D frag mapping col = c15, row = g*4 + r
  if (EPI == 0) {
    const float SCALE = 0.17677669529663687f;      // 32^-0.5
    const int win0 = (brow + wr * 128) >> 6;       // first window of this wave
#pragma unroll
    for (int n = 0; n < 4; ++n) {
      int c = bcol + wc * 64 + n * 16 + c15;       // 0..1535
      float bz = bias[c];
      int which = c >> 9;                          // block-uniform: 0=q 1=k 2=v
      int cq = c & 511, h = cq >> 5, d = cq & 31;
      size_t pb0 = ((size_t)(win0 * NHEAD + h)) << 11;   // (win,head) slab, 2048 elems
      size_t pb1 = pb0 + ((size_t)NHEAD << 11);          // win0+1
      if (which == 2) {
        u16* v0 = vws + pb0 + (d << 6);
        u16* v1 = vws + pb1 + (d << 6);
#pragma unroll
        for (int i = 0; i < 8; ++i) {
          u16* vp = (i < 4) ? v0 : v1;
#pragma unroll
          for (int r = 0; r < 4; ++r) {
            int tok = (i & 3) * 16 + g * 4 + r;
            vp[tok] = f2bf(acc[i][n][r] + bz);
          }
        }
      } else {
        const float s = (which == 0) ? SCALE : 1.0f;
        u16* base = (which == 0) ? qws : kws;
        u16* q0 = base + pb0 + d;
        u16* q1 = base + pb1 + d;
#pragma unroll
        for (int i = 0; i < 8; ++i) {
          u16* qp = (i < 4) ? q0 : q1;
#pragma unroll
          for (int r = 0; r < 4; ++r) {
            int tok = (i & 3) * 16 + g * 4 + r;
            qp[tok << 5] = f2bf((acc[i][n][r] + bz) * s);
          }
        }
      }
    }
  } else {
#pragma unroll
    for (int n = 0; n < 4; ++n) {
      int c = bcol + wc * 64 + n * 16 + c15;
      float bz = bias[c];
      float* po = out + (size_t)(brow + wr * 128) * CDIM + c;
#pragma unroll
      for (int i = 0; i < 8; ++i)
#pragma unroll
        for (int r = 0; r < 4; ++r)
          po[(size_t)(i * 16 + g * 4 + r) * CDIM] = acc[i][n][r] + bz;
    }
  }
}

// ---------------------------------------------------------------------------
// attention: 1 wave per (window, head). S^T = mfma(K,Q); softmax in-lane+2shfl;
// bias+mask from combined bf16 table (row-major -> one uint2 load per jt);
// P -> swizzled LDS -> A-frags; out = P@V via vT; y stored bf16 [b][tok][C]
// ---------------------------------------------------------------------------
__global__ __launch_bounds__(256) void k_attn(const u16* __restrict__ qws,
                                              const u16* __restrict__ kws,
                                              const u16* __restrict__ vws,
                                              const u16* __restrict__ combB,
                                              u16* __restrict__ yws) {
  __shared__ __align__(16) u16 plds[4][NTOK * NTOK];  // 8 KiB per wave
  const int tid = threadIdx.x, w = tid >> 6, lane = tid & 63;
  const int c15 = lane & 15, g = lane >> 4, g4 = g * 4;
  const int p = blockIdx.x * 4 + w;
  const int b = p >> 4, h = p & 15;

  const u16* qb_ = qws + (size_t)p * (NTOK * HDIM);
  const u16* kb_ = kws + (size_t)p * (NTOK * HDIM);
  bfrag qa[4], ka[4];
#pragma unroll
  for (int t = 0; t < 4; ++t) {
    qa[t] = *reinterpret_cast<const bfrag*>(qb_ + (t * 16 + c15) * HDIM + g * 8);
    ka[t] = *reinterpret_cast<const bfrag*>(kb_ + (t * 16 + c15) * HDIM + g * 8);
  }

  const u16* cB = combB + ((size_t)(((b & (NW - 1)) << 4) + h) << 12);  // [row][col]
  u16* pl = plds[w];
  const ffrag zf = {0.f, 0.f, 0.f, 0.f};

#pragma unroll
  for (int it = 0; it < 4; ++it) {
    int row = it * 16 + c15;           // score row
    float l[4][4];
    float mx = -3.0e38f;
#pragma unroll
    for (int jt = 0; jt < 4; ++jt) {
      ffrag s = mfma16(ka[jt], qa[it], zf);   // S^T tile: D[4g+r][c15]
      uint2 cw = *reinterpret_cast<const uint2*>(cB + row * 64 + jt * 16 + g4);
      float c0 = bfhi2f(cw.x << 16);
      float c1 = bfhi2f(cw.x & 0xffff0000u);
      float c2 = bfhi2f(cw.y << 16);
      float c3 = bfhi2f(cw.y & 0xffff0000u);
      l[jt][0] = s[0] + c0;
      l[jt][1] = s[1] + c1;
      l[jt][2] = s[2] + c2;
      l[jt][3] = s[3] + c3;
      mx = fmaxf(mx, fmaxf(fmaxf(l[jt][0], l[jt][1]), fmaxf(l[jt][2], l[jt][3])));
    }
    mx = fmaxf(mx, __shfl_xor(mx, 16));
    mx = fmaxf(mx, __shfl_xor(mx, 32));
    float sum = 0.f;
#pragma unroll
    for (int jt = 0; jt < 4; ++jt)
#pragma unroll
      for (int r = 0; r < 4; ++r) {
        float e = __expf(l[jt][r] - mx);
        l[jt][r] = e;
        sum += e;
      }
    sum += __shfl_xor(sum, 16);
    sum += __shfl_xor(sum, 32);
    float inv = 1.0f / sum;
#pragma unroll
    for (int jt = 0; jt < 4; ++jt) {
      union { u16 u[4]; uint2 v; } pk;
#pragma unroll
      for (int r = 0; r < 4; ++r) pk.u[r] = f2bf(l[jt][r] * inv);
      int off = row * 64 + ((jt * 16 + g4) ^ ((row & 7) << 3));
      *reinterpret_cast<uint2*>(&pl[off]) = pk.v;
    }
  }
  __syncthreads();

  const u16* vb_ = vws + (size_t)p * (HDIM * NTOK);
#pragma unroll
  for (int ct = 0; ct < 2; ++ct) {
    ffrag o[4] = {zf, zf, zf, zf};
#pragma unroll
    for (int ks = 0; ks < 2; ++ks) {
      bfrag vf = *reinterpret_cast<const bfrag*>(vb_ + (ct * 16 + c15) * NTOK + ks * 32 + g * 8);
#pragma unroll
      for (int i = 0; i < 4; ++i) {
        int prow = i * 16 + c15;
        bfrag pa = *reinterpret_cast<const bfrag*>(
            &pl[prow * 64 + ((ks * 32 + g * 8) ^ ((prow & 7) << 3))]);
        o[i] = mfma16(pa, vf, o[i]);
      }
    }
#pragma unroll
    for (int i = 0; i < 4; ++i)
#pragma unroll
      for (int r = 0; r < 4; ++r) {
        int tok = i * 16 + g4 + r;
        yws[((size_t)b * NTOK + tok) * CDIM + h * HDIM + ct * 16 + c15] = f2bf(o[i][r]);
      }
  }
}

// ---------------------------------------------------------------------------
extern "C" void kernel_launch(void* const* d_in, const int* in_sizes, int n_in,
                              void* d_out, int out_size, void* d_ws, size_t ws_size,
                              hipStream_t stream) {
  const float* x      = (const float*)d_in[0];
  const float* mask   = (const float*)d_in[1];
  const float* qkv_w  = (const float*)d_in[2];
  const float* qkv_b  = (const float*)d_in[3];
  const float* proj_w = (const float*)d_in[4];
  const float* proj_b = (const float*)d_in[5];
  const float* rpb    = (const float*)d_in[6];
  const int*   rel    = (const int*)d_in[7];
  float* out = (float*)d_out;

  char* ws = (char*)d_ws;
  constexpr size_t SZ_QKV = (size_t)NWIN_TOT * NHEAD * NTOK * HDIM * 2;  // 64 MiB each
  u16* qws = (u16*)(ws);
  u16* kws = (u16*)(ws + SZ_QKV);
  u16* vws = (u16*)(ws + 2 * SZ_QKV);
  u16* xb  = (u16*)(ws + 3 * SZ_QKV);   // x as bf16; dead after k_gemm8<0> ...
  u16* yws = xb;                        // ... so yws aliases it (written in k_attn)
  u16* wq  = (u16*)(ws + 4 * SZ_QKV);
  u16* wp  = (u16*)(ws + 4 * SZ_QKV + 1572864);
  u16* combB = (u16*)(ws + 4 * SZ_QKV + 1572864 + 524288);  // 8 MiB

  hipFuncSetAttribute((const void*)k_gemm8<0>,
                      hipFuncAttributeMaxDynamicSharedMemorySize, 131072);
  hipFuncSetAttribute((const void*)k_gemm8<1>,
                      hipFuncAttributeMaxDynamicSharedMemorySize, 131072);

  k_prep<<<dim3(36864), dim3(256), 0, stream>>>(x, qkv_w, proj_w, rel, rpb, mask,
                                                xb, wq, wp, combB);
  k_gemm8<0><<<dim3(256 * 6), dim3(512), 131072, stream>>>(xb, wq, qkv_b, qws, kws, vws, nullptr);
  k_attn<<<dim3(NWIN_TOT * NHEAD / 4), dim3(256), 0, stream>>>(qws, kws, vws, combB, yws);
  k_gemm8<1><<<dim3(256 * 2), dim3(512), 131072, stream>>>(yws, wp, proj_b, nullptr, nullptr, nullptr, out);
}